// Round 2
// baseline (157.762 us; speedup 1.0000x reference)
//
#include <hip/hip_runtime.h>
#include <hip/hip_bf16.h>
#include <math.h>

#define B_ 4096
#define F_ 64
#define A_ 8
#define U_ 32

typedef float f32x4 __attribute__((ext_vector_type(4)));
typedef short bf16x8 __attribute__((ext_vector_type(8)));

// ws layout:
//   [0, 4 MB): frag blob, per (a,j) 8192 B, index (a*64+j):
//     [0,4096):  K B-frags, fragid = kc*2+ut, 64 lanes x 16 B:
//                bf16 K[f = kc*32 + q*8 + jj][u = ut*16 + c]
//     [4096,8192): W B-frags, fragid = ft:
//                bf16 exp(2*K[f = ft*16 + c][u = q*8 + jj])
//   [4 MB, 4 MB + 64 KB): Kd fp32 (bf16-rounded values): [a*64+j][32] = K[j,a][j][u]
#define KD_OFF (4ull << 20)

static __device__ __forceinline__ unsigned int pk_bf16(float lo, float hi) {
    union { __hip_bfloat162 h2; unsigned int u; } cv;
    cv.h2 = __float22bfloat162_rn(make_float2(lo, hi));
    return cv.u;
}
// round fp32 -> bf16 -> fp32 (match what the MFMA actually sees)
static __device__ __forceinline__ float rb(float f) {
    unsigned int u = __float_as_uint(f);
    u += 0x7FFFu + ((u >> 16) & 1u);
    return __uint_as_float(u & 0xFFFF0000u);
}

// ---------------- prep: one block per (a,j); stage 8 KB, emit frags + Kd ----------------
__global__ __launch_bounds__(256) void ife_prep(const float* __restrict__ kern,
                                                unsigned char* __restrict__ ws)
{
    const int bid = blockIdx.x;           // a*64 + j
    const int a = bid >> 6, j = bid & 63;
    const int t = threadIdx.x;
    __shared__ float st[64][36];          // [f][u], pitch 36 (16B-aligned float4 slots)

    const float* src = kern + ((size_t)j * A_ + a) * (F_ * U_);
    {
        const int f = t >> 2, u0 = (t & 3) * 8;
        *(float4*)&st[f][u0]     = *(const float4*)&src[f * U_ + u0];
        *(float4*)&st[f][u0 + 4] = *(const float4*)&src[f * U_ + u0 + 4];
    }
    __syncthreads();

    unsigned char* dst = ws + (size_t)bid * 8192;
    const int fragid = t >> 6, lane = t & 63, q = lane >> 4, c = lane & 15;

    // K B-frag (fragid = kc*2 + ut)
    {
        const int kc = fragid >> 1, ut = fragid & 1;
        const int f0 = kc * 32 + q * 8, u = ut * 16 + c;
        unsigned int w[4];
        #pragma unroll
        for (int i = 0; i < 4; ++i)
            w[i] = pk_bf16(st[f0 + 2 * i][u], st[f0 + 2 * i + 1][u]);
        *(uint4*)(dst + fragid * 1024 + lane * 16) = make_uint4(w[0], w[1], w[2], w[3]);
    }
    // W B-frag (fragid = ft)
    {
        const int f = fragid * 16 + c, u0 = q * 8;
        const float4 wa = *(const float4*)&st[f][u0];
        const float4 wb = *(const float4*)&st[f][u0 + 4];
        unsigned int w[4];
        w[0] = pk_bf16(__expf(2.f * wa.x), __expf(2.f * wa.y));
        w[1] = pk_bf16(__expf(2.f * wa.z), __expf(2.f * wa.w));
        w[2] = pk_bf16(__expf(2.f * wb.x), __expf(2.f * wb.y));
        w[3] = pk_bf16(__expf(2.f * wb.z), __expf(2.f * wb.w));
        *(uint4*)(dst + 4096 + fragid * 1024 + lane * 16) = make_uint4(w[0], w[1], w[2], w[3]);
    }
    // Kd (bf16-rounded so the rank-1 correction exactly cancels the MFMA j-term)
    if (t < U_)
        ((float*)(ws + KD_OFF))[(size_t)bid * U_ + t] = rb(st[j][t]);
}

// ---------------- main: (a, 64-row tile); 8 waves = 2 j-groups x 4 row-waves ----------------
// Wave-group g (waves 4g..4g+3) processes j in [32g, 32g+32) over the SAME 64-row tile;
// partial S accumulators are combined through LDS (reusing Pbuf) before the epilogue.
// This doubles occupancy (2 -> 4 waves/SIMD) to hide the per-j serial chain:
//   Z-MFMA -> exp -> LDS write -> LDS read -> PV-MFMA.
__global__ __launch_bounds__(512, 4) void ife_main(const float* __restrict__ x,
                                                   const unsigned char* __restrict__ ws,
                                                   float* __restrict__ out)
{
    const int a = blockIdx.y, bt = blockIdx.x, t = threadIdx.x;
    const int wv = t >> 6, lane = t & 63, q = lane >> 4, c = lane & 15;
    const int grp = wv >> 2, w4 = wv & 3;

    __shared__ float Xf[64][66];                       // bf16-rounded fp32 X tile
    __shared__ float Kd[64][32];                       // bf16-rounded K[j][j][u] for this a
    __shared__ __align__(16) unsigned int Pbuf[2][8][16][20];  // wave-private E, dbuf; 20.5 KB

    // X A-frags (m = c, k = kc*32 + q*8 + jj), pure bf16 — per wave, rows w4*16..
    bf16x8 Xh[2];
    {
        const float* xr = x + (size_t)(bt * 64 + w4 * 16 + c) * F_;
        #pragma unroll
        for (int kc = 0; kc < 2; ++kc) {
            const float4 va = *(const float4*)&xr[kc * 32 + q * 8];
            const float4 vb = *(const float4*)&xr[kc * 32 + q * 8 + 4];
            union { unsigned int u[4]; bf16x8 v; } H;
            H.u[0] = pk_bf16(va.x, va.y);
            H.u[1] = pk_bf16(va.z, va.w);
            H.u[2] = pk_bf16(vb.x, vb.y);
            H.u[3] = pk_bf16(vb.z, vb.w);
            Xh[kc] = H.v;
        }
    }
    // Xf (bf16-rounded values, fp32 storage, broadcast-friendly); 512 threads
    {
        const int row = t >> 3, cb = (t & 7) * 8;
        const float* xsrc = x + (size_t)(bt * 64 + row) * F_ + cb;
        const float4 v0 = *(const float4*)&xsrc[0];
        const float4 v1 = *(const float4*)&xsrc[4];
        Xf[row][cb + 0] = rb(v0.x); Xf[row][cb + 1] = rb(v0.y);
        Xf[row][cb + 2] = rb(v0.z); Xf[row][cb + 3] = rb(v0.w);
        Xf[row][cb + 4] = rb(v1.x); Xf[row][cb + 5] = rb(v1.y);
        Xf[row][cb + 6] = rb(v1.z); Xf[row][cb + 7] = rb(v1.w);
    }
    // Kd stage (contiguous 8 KB); 512 threads x 1 float4
    {
        const float* kd = (const float*)(ws + KD_OFF) + (size_t)a * 64 * U_;
        const int jj = t >> 3, u0 = (t & 7) * 4;
        *(float4*)&Kd[jj][u0] = *(const float4*)&kd[jj * U_ + u0];
    }
    __syncthreads();   // staging barrier

    const unsigned int psel = (q < 2) ? 0x05040100u : 0x07060302u;
    const unsigned char* fbase = ws + (size_t)a * 64 * 8192 + (size_t)lane * 16;

    union { unsigned int u[4]; bf16x8 v; } oc;
    oc.u[0] = 0x3F803F80u; oc.u[1] = 0x3F803F80u; oc.u[2] = 0x3F803F80u; oc.u[3] = 0x3F803F80u;
    const bf16x8 ONES = oc.v;
    const f32x4 vzero = (f32x4){0.f, 0.f, 0.f, 0.f};

    f32x4 S0 = vzero, S1 = vzero, S2 = vzero, S3 = vzero;

    bf16x8 KA[4], WA[4], KB[4], WB[4];
    float xjA[4], xjB[4], kdA0, kdA1, kdB0, kdB1;
    uint4 ra0, ra1, rb0, rb1;

    auto LOADF = [&](bf16x8* K, bf16x8* W, int jj) {
        const unsigned char* p = fbase + (size_t)jj * 8192;
        #pragma unroll
        for (int i = 0; i < 4; ++i) {
            K[i] = *(const bf16x8*)(p + i * 1024);
            W[i] = *(const bf16x8*)(p + 4096 + i * 1024);
        }
    };

    // per-j scalars (LDS broadcast reads), prefetched one iteration ahead
    auto SCAL = [&](float* xj, float& k0, float& k1, int j) {
        #pragma unroll
        for (int r = 0; r < 4; ++r) xj[r] = Xf[w4 * 16 + q * 4 + r][j];
        k0 = Kd[j][c];
        k1 = Kd[j][16 + c];
    };

    // stage 1: Z = X@K (MFMA), rank-1 mask correction + exp, write unnormalized E to LDS
    auto ZW = [&](const bf16x8* K, const float* xj, float kd0, float kd1,
                  unsigned int (*P)[16][20]) {
        f32x4 ZA = vzero, ZB = vzero;
        ZA = __builtin_amdgcn_mfma_f32_16x16x32_bf16(Xh[0], K[0], ZA, 0, 0, 0);
        ZA = __builtin_amdgcn_mfma_f32_16x16x32_bf16(Xh[1], K[2], ZA, 0, 0, 0);
        ZB = __builtin_amdgcn_mfma_f32_16x16x32_bf16(Xh[0], K[1], ZB, 0, 0, 0);
        ZB = __builtin_amdgcn_mfma_f32_16x16x32_bf16(Xh[1], K[3], ZB, 0, 0, 0);
        #pragma unroll
        for (int r = 0; r < 4; ++r) {
            const float e0 = __expf(ZA[r] - xj[r] * kd0);
            const float e1 = __expf(ZB[r] - xj[r] * kd1);
            P[wv][q * 4 + r][c] = pk_bf16(e0, e1);
        }
    };

    // stage 2a: issue the transposed read-back of E (latency hides under next ZW)
    auto RD = [&](uint4& pa, uint4& pb, const unsigned int (*P)[16][20]) {
        asm volatile("" ::: "memory");   // pin order vs preceding ds_writes
        pa = *(const uint4*)&P[wv][c][(q & 1) * 8];
        pb = *(const uint4*)&P[wv][c][(q & 1) * 8 + 4];
        asm volatile("" ::: "memory");   // keep the reads from sinking past next ZW
    };

    // stage 2b: perm-deinterleave, row sums via MFMA vs ones, PV MFMAs, normalize+accumulate
    auto FN = [&](const uint4& pa, const uint4& pb, const bf16x8* W) {
        union { unsigned int u[4]; bf16x8 v; } E;
        E.u[0] = __builtin_amdgcn_perm(pa.y, pa.x, psel);
        E.u[1] = __builtin_amdgcn_perm(pa.w, pa.z, psel);
        E.u[2] = __builtin_amdgcn_perm(pb.y, pb.x, psel);
        E.u[3] = __builtin_amdgcn_perm(pb.w, pb.z, psel);

        const f32x4 sv = __builtin_amdgcn_mfma_f32_16x16x32_bf16(E.v, ONES, vzero, 0, 0, 0);
        f32x4 D0 = __builtin_amdgcn_mfma_f32_16x16x32_bf16(E.v, W[0], vzero, 0, 0, 0);
        f32x4 D1 = __builtin_amdgcn_mfma_f32_16x16x32_bf16(E.v, W[1], vzero, 0, 0, 0);
        f32x4 D2 = __builtin_amdgcn_mfma_f32_16x16x32_bf16(E.v, W[2], vzero, 0, 0, 0);
        f32x4 D3 = __builtin_amdgcn_mfma_f32_16x16x32_bf16(E.v, W[3], vzero, 0, 0, 0);
        #pragma unroll
        for (int r = 0; r < 4; ++r) {
            const float inv = __builtin_amdgcn_rcpf(sv[r]);
            S0[r] += D0[r] * inv;
            S1[r] += D1[r] * inv;
            S2[r] += D2[r] * inv;
            S3[r] += D3[r] * inv;
        }
    };

    // ---- pipeline over this group's 32 j values ----
    const int jb = grp * 32;
    LOADF(KA, WA, jb);
    SCAL(xjA, kdA0, kdA1, jb);
    ZW(KA, xjA, kdA0, kdA1, Pbuf[0]);
    LOADF(KB, WB, jb + 1);
    SCAL(xjB, kdB0, kdB1, jb + 1);

    for (int j = 0; j < 30; j += 2) {
        RD(ra0, ra1, Pbuf[0]);                  // E_{jb+j}
        ZW(KB, xjB, kdB0, kdB1, Pbuf[1]);       // Z(jb+j+1) -> P1; hides read latency
        FN(ra0, ra1, WA);                       // finish jb+j
        LOADF(KA, WA, jb + j + 2);
        SCAL(xjA, kdA0, kdA1, jb + j + 2);
        RD(rb0, rb1, Pbuf[1]);                  // E_{jb+j+1}
        ZW(KA, xjA, kdA0, kdA1, Pbuf[0]);       // Z(jb+j+2) -> P0
        FN(rb0, rb1, WB);                       // finish jb+j+1
        LOADF(KB, WB, jb + j + 3);              // j <= 28 so jb+j+3 <= jb+31
        SCAL(xjB, kdB0, kdB1, jb + j + 3);
    }
    // tail: P0 holds E_{jb+30}, B set holds jb+31, WA holds W_{jb+30}
    RD(ra0, ra1, Pbuf[0]);
    ZW(KB, xjB, kdB0, kdB1, Pbuf[1]);           // Z(jb+31) -> P1
    FN(ra0, ra1, WA);                           // finish jb+30
    RD(rb0, rb1, Pbuf[1]);
    FN(rb0, rb1, WB);                           // finish jb+31

    // ---- combine the two j-groups' partial S through LDS (reuse Pbuf: 20.4 KB >= 20.4 KB) ----
    __syncthreads();                            // all Pbuf reads done
    float* Sred = (float*)Pbuf;                 // [w4*64+lane][20] pitch: 80 B rows, 16B-aligned
    if (grp == 1) {
        float* p = Sred + (size_t)(w4 * 64 + lane) * 20;
        *(f32x4*)(p + 0)  = S0;
        *(f32x4*)(p + 4)  = S1;
        *(f32x4*)(p + 8)  = S2;
        *(f32x4*)(p + 12) = S3;
    }
    __syncthreads();
    if (grp == 0) {
        const float* p = Sred + (size_t)(w4 * 64 + lane) * 20;
        S0 += *(const f32x4*)(p + 0);
        S1 += *(const f32x4*)(p + 4);
        S2 += *(const f32x4*)(p + 8);
        S3 += *(const f32x4*)(p + 12);

        // epilogue: mean over j, softmax over f (flat scores -> no max needed)
        const float sc = 1.f / 64.f;
        #pragma unroll
        for (int r = 0; r < 4; ++r) {
            const float e0 = __expf(S0[r] * sc);
            const float e1 = __expf(S1[r] * sc);
            const float e2 = __expf(S2[r] * sc);
            const float e3 = __expf(S3[r] * sc);
            float s = e0 + e1 + e2 + e3;
            s += __shfl_xor(s, 1);
            s += __shfl_xor(s, 2);
            s += __shfl_xor(s, 4);
            s += __shfl_xor(s, 8);
            const float inv = 1.f / s;
            const int b = bt * 64 + w4 * 16 + q * 4 + r;
            float* o = out + ((size_t)a * B_ + b) * F_ + c;
            o[0]  = e0 * inv;
            o[16] = e1 * inv;
            o[32] = e2 * inv;
            o[48] = e3 * inv;
        }
    }
}

extern "C" void kernel_launch(void* const* d_in, const int* in_sizes, int n_in,
                              void* d_out, int out_size, void* d_ws, size_t ws_size,
                              hipStream_t stream) {
    (void)in_sizes; (void)n_in; (void)out_size; (void)ws_size;
    const float* x    = (const float*)d_in[0];   // [B, F]
    const float* kern = (const float*)d_in[1];   // [F, A, F, U]
    float* out        = (float*)d_out;           // [A, B, F]
    unsigned char* ws = (unsigned char*)d_ws;    // ~4.1 MB used

    hipLaunchKernelGGL(ife_prep, dim3(F_ * A_), dim3(256), 0, stream, kern, ws);
    hipLaunchKernelGGL(ife_main, dim3(B_ / 64, A_), dim3(512), 0, stream, x, ws, out);
}

// Round 3
// 103.590 us; speedup vs baseline: 1.5230x; 1.5230x over previous
//
#include <hip/hip_runtime.h>
#include <hip/hip_bf16.h>
#include <math.h>

#define B_ 4096
#define F_ 64
#define A_ 8
#define U_ 32

typedef float f32x4 __attribute__((ext_vector_type(4)));
typedef short bf16x8 __attribute__((ext_vector_type(8)));

// ws layout:
//   [0, 4 MB): frag blob, per (a,j) 8192 B, index (a*64+j):
//     [0,4096):  K B-frags, fragid = kc*2+ut, 64 lanes x 16 B:
//                bf16 K[f = kc*32 + q*8 + jj][u = ut*16 + c]
//     [4096,8192): W B-frags, fragid = ft:
//                bf16 exp(2*K[f = ft*16 + c][u = q*8 + jj])
//   [4 MB, 4 MB + 64 KB): Kd fp32 (bf16-rounded values): [a*64+j][32] = K[j,a][j][u]
#define KD_OFF (4ull << 20)

static __device__ __forceinline__ unsigned int pk_bf16(float lo, float hi) {
    union { __hip_bfloat162 h2; unsigned int u; } cv;
    cv.h2 = __float22bfloat162_rn(make_float2(lo, hi));
    return cv.u;
}
// round fp32 -> bf16 -> fp32 (match what the MFMA actually sees)
static __device__ __forceinline__ float rb(float f) {
    unsigned int u = __float_as_uint(f);
    u += 0x7FFFu + ((u >> 16) & 1u);
    return __uint_as_float(u & 0xFFFF0000u);
}

// ---------------- prep: one block per (a,j); stage 8 KB, emit frags + Kd ----------------
__global__ __launch_bounds__(256) void ife_prep(const float* __restrict__ kern,
                                                unsigned char* __restrict__ ws)
{
    const int bid = blockIdx.x;           // a*64 + j
    const int a = bid >> 6, j = bid & 63;
    const int t = threadIdx.x;
    __shared__ float st[64][36];          // [f][u], pitch 36 (16B-aligned float4 slots)

    const float* src = kern + ((size_t)j * A_ + a) * (F_ * U_);
    {
        const int f = t >> 2, u0 = (t & 3) * 8;
        *(float4*)&st[f][u0]     = *(const float4*)&src[f * U_ + u0];
        *(float4*)&st[f][u0 + 4] = *(const float4*)&src[f * U_ + u0 + 4];
    }
    __syncthreads();

    unsigned char* dst = ws + (size_t)bid * 8192;
    const int fragid = t >> 6, lane = t & 63, q = lane >> 4, c = lane & 15;

    // K B-frag (fragid = kc*2 + ut)
    {
        const int kc = fragid >> 1, ut = fragid & 1;
        const int f0 = kc * 32 + q * 8, u = ut * 16 + c;
        unsigned int w[4];
        #pragma unroll
        for (int i = 0; i < 4; ++i)
            w[i] = pk_bf16(st[f0 + 2 * i][u], st[f0 + 2 * i + 1][u]);
        *(uint4*)(dst + fragid * 1024 + lane * 16) = make_uint4(w[0], w[1], w[2], w[3]);
    }
    // W B-frag (fragid = ft)
    {
        const int f = fragid * 16 + c, u0 = q * 8;
        const float4 wa = *(const float4*)&st[f][u0];
        const float4 wb = *(const float4*)&st[f][u0 + 4];
        unsigned int w[4];
        w[0] = pk_bf16(__expf(2.f * wa.x), __expf(2.f * wa.y));
        w[1] = pk_bf16(__expf(2.f * wa.z), __expf(2.f * wa.w));
        w[2] = pk_bf16(__expf(2.f * wb.x), __expf(2.f * wb.y));
        w[3] = pk_bf16(__expf(2.f * wb.z), __expf(2.f * wb.w));
        *(uint4*)(dst + 4096 + fragid * 1024 + lane * 16) = make_uint4(w[0], w[1], w[2], w[3]);
    }
    // Kd (bf16-rounded so the rank-1 correction exactly cancels the MFMA j-term)
    if (t < U_)
        ((float*)(ws + KD_OFF))[(size_t)bid * U_ + t] = rb(st[j][t]);
}

// ---------------- main: (a, 64-row tile); 8 waves = 2 j-groups x 4 row-waves ----------------
// Wave-group g processes j in [32g, 32g+32) over the SAME 64-row tile; partial S combined
// through LDS at the end. 4 waves/SIMD provide the latency hiding (TLP); the loop body is
// deliberately register-lean (single frag set, single wave-private Pbuf, no manual pipeline)
// so it fits the 128-VGPR cap of __launch_bounds__(512,4) without scratch spills (R2 lesson).
__global__ __launch_bounds__(512, 4) void ife_main(const float* __restrict__ x,
                                                   const unsigned char* __restrict__ ws,
                                                   float* __restrict__ out)
{
    const int a = blockIdx.y, bt = blockIdx.x, t = threadIdx.x;
    const int wv = t >> 6, lane = t & 63, q = lane >> 4, c = lane & 15;
    const int grp = wv >> 2, w4 = wv & 3;

    __shared__ __align__(16) float Xf[64][66];         // bf16-rounded fp32 X tile (16.9 KB)
    __shared__ float Kd[64][32];                       // bf16-rounded K[j][j][u] (8 KB)
    __shared__ __align__(16) unsigned int Pbuf[8][16][20];  // wave-private E (10 KB)

    // X A-frags (m = c, k = kc*32 + q*8 + jj), pure bf16 — per wave, rows w4*16..
    bf16x8 Xh[2];
    {
        const float* xr = x + (size_t)(bt * 64 + w4 * 16 + c) * F_;
        #pragma unroll
        for (int kc = 0; kc < 2; ++kc) {
            const float4 va = *(const float4*)&xr[kc * 32 + q * 8];
            const float4 vb = *(const float4*)&xr[kc * 32 + q * 8 + 4];
            union { unsigned int u[4]; bf16x8 v; } H;
            H.u[0] = pk_bf16(va.x, va.y);
            H.u[1] = pk_bf16(va.z, va.w);
            H.u[2] = pk_bf16(vb.x, vb.y);
            H.u[3] = pk_bf16(vb.z, vb.w);
            Xh[kc] = H.v;
        }
    }
    // Xf (bf16-rounded values, fp32 storage, broadcast-friendly); 512 threads
    {
        const int row = t >> 3, cb = (t & 7) * 8;
        const float* xsrc = x + (size_t)(bt * 64 + row) * F_ + cb;
        const float4 v0 = *(const float4*)&xsrc[0];
        const float4 v1 = *(const float4*)&xsrc[4];
        Xf[row][cb + 0] = rb(v0.x); Xf[row][cb + 1] = rb(v0.y);
        Xf[row][cb + 2] = rb(v0.z); Xf[row][cb + 3] = rb(v0.w);
        Xf[row][cb + 4] = rb(v1.x); Xf[row][cb + 5] = rb(v1.y);
        Xf[row][cb + 6] = rb(v1.z); Xf[row][cb + 7] = rb(v1.w);
    }
    // Kd stage (contiguous 8 KB); 512 threads x 1 float4
    {
        const float* kd = (const float*)(ws + KD_OFF) + (size_t)a * 64 * U_;
        const int jj = t >> 3, u0 = (t & 7) * 4;
        *(float4*)&Kd[jj][u0] = *(const float4*)&kd[jj * U_ + u0];
    }
    __syncthreads();   // staging barrier

    const unsigned int psel = (q < 2) ? 0x05040100u : 0x07060302u;
    const unsigned char* fbase = ws + (size_t)a * 64 * 8192 + (size_t)lane * 16;

    union { unsigned int u[4]; bf16x8 v; } oc;
    oc.u[0] = 0x3F803F80u; oc.u[1] = 0x3F803F80u; oc.u[2] = 0x3F803F80u; oc.u[3] = 0x3F803F80u;
    const bf16x8 ONES = oc.v;
    const f32x4 vzero = (f32x4){0.f, 0.f, 0.f, 0.f};

    f32x4 S0 = vzero, S1 = vzero, S2 = vzero, S3 = vzero;

    const int jb = grp * 32;
    #pragma unroll 1
    for (int jj = 0; jj < 32; ++jj) {
        const int j = jb + jj;

        // frag loads (global, L2/L3-resident blob)
        bf16x8 K[4], W[4];
        {
            const unsigned char* p = fbase + (size_t)j * 8192;
            #pragma unroll
            for (int i = 0; i < 4; ++i) {
                K[i] = *(const bf16x8*)(p + i * 1024);
                W[i] = *(const bf16x8*)(p + 4096 + i * 1024);
            }
        }
        // per-j scalars (LDS broadcast reads)
        float xj[4];
        #pragma unroll
        for (int r = 0; r < 4; ++r) xj[r] = Xf[w4 * 16 + q * 4 + r][j];
        const float kd0 = Kd[j][c], kd1 = Kd[j][16 + c];

        // Z = X @ K (pure bf16)
        f32x4 ZA = vzero, ZB = vzero;
        ZA = __builtin_amdgcn_mfma_f32_16x16x32_bf16(Xh[0], K[0], ZA, 0, 0, 0);
        ZA = __builtin_amdgcn_mfma_f32_16x16x32_bf16(Xh[1], K[2], ZA, 0, 0, 0);
        ZB = __builtin_amdgcn_mfma_f32_16x16x32_bf16(Xh[0], K[1], ZB, 0, 0, 0);
        ZB = __builtin_amdgcn_mfma_f32_16x16x32_bf16(Xh[1], K[3], ZB, 0, 0, 0);

        // rank-1 mask correction + exp (no max subtraction), write unnormalized E
        #pragma unroll
        for (int r = 0; r < 4; ++r) {
            const float e0 = __expf(ZA[r] - xj[r] * kd0);
            const float e1 = __expf(ZB[r] - xj[r] * kd1);
            Pbuf[wv][q * 4 + r][c] = pk_bf16(e0, e1);
        }
        // wave-internal LDS round-trip: drain writes, then read A-frag (transposed)
        asm volatile("s_waitcnt lgkmcnt(0)" ::: "memory");
        const uint4 pa = *(const uint4*)&Pbuf[wv][c][(q & 1) * 8];
        const uint4 pb = *(const uint4*)&Pbuf[wv][c][(q & 1) * 8 + 4];

        union { unsigned int u[4]; bf16x8 v; } E;
        E.u[0] = __builtin_amdgcn_perm(pa.y, pa.x, psel);
        E.u[1] = __builtin_amdgcn_perm(pa.w, pa.z, psel);
        E.u[2] = __builtin_amdgcn_perm(pb.y, pb.x, psel);
        E.u[3] = __builtin_amdgcn_perm(pb.w, pb.z, psel);

        // row sums via MFMA against ones; normalize after the GEMM
        const f32x4 sv = __builtin_amdgcn_mfma_f32_16x16x32_bf16(E.v, ONES, vzero, 0, 0, 0);
        f32x4 D0 = __builtin_amdgcn_mfma_f32_16x16x32_bf16(E.v, W[0], vzero, 0, 0, 0);
        f32x4 D1 = __builtin_amdgcn_mfma_f32_16x16x32_bf16(E.v, W[1], vzero, 0, 0, 0);
        f32x4 D2 = __builtin_amdgcn_mfma_f32_16x16x32_bf16(E.v, W[2], vzero, 0, 0, 0);
        f32x4 D3 = __builtin_amdgcn_mfma_f32_16x16x32_bf16(E.v, W[3], vzero, 0, 0, 0);
        #pragma unroll
        for (int r = 0; r < 4; ++r) {
            const float inv = __builtin_amdgcn_rcpf(sv[r]);
            S0[r] += D0[r] * inv;
            S1[r] += D1[r] * inv;
            S2[r] += D2[r] * inv;
            S3[r] += D3[r] * inv;
        }
    }

    // ---- combine the two j-groups' partial S through LDS (reuse Xf: 16.4 KB <= 16.9 KB) ----
    __syncthreads();                            // all Xf/Kd/Pbuf reads done
    float* Sred = (float*)Xf;                   // [w4*64+lane][16], 16B-aligned rows
    if (grp == 1) {
        float* p = Sred + (size_t)(w4 * 64 + lane) * 16;
        *(f32x4*)(p + 0)  = S0;
        *(f32x4*)(p + 4)  = S1;
        *(f32x4*)(p + 8)  = S2;
        *(f32x4*)(p + 12) = S3;
    }
    __syncthreads();
    if (grp == 0) {
        const float* p = Sred + (size_t)(w4 * 64 + lane) * 16;
        S0 += *(const f32x4*)(p + 0);
        S1 += *(const f32x4*)(p + 4);
        S2 += *(const f32x4*)(p + 8);
        S3 += *(const f32x4*)(p + 12);

        // epilogue: mean over j, softmax over f (flat scores -> no max needed)
        const float sc = 1.f / 64.f;
        #pragma unroll
        for (int r = 0; r < 4; ++r) {
            const float e0 = __expf(S0[r] * sc);
            const float e1 = __expf(S1[r] * sc);
            const float e2 = __expf(S2[r] * sc);
            const float e3 = __expf(S3[r] * sc);
            float s = e0 + e1 + e2 + e3;
            s += __shfl_xor(s, 1);
            s += __shfl_xor(s, 2);
            s += __shfl_xor(s, 4);
            s += __shfl_xor(s, 8);
            const float inv = 1.f / s;
            const int b = bt * 64 + w4 * 16 + q * 4 + r;
            float* o = out + ((size_t)a * B_ + b) * F_ + c;
            o[0]  = e0 * inv;
            o[16] = e1 * inv;
            o[32] = e2 * inv;
            o[48] = e3 * inv;
        }
    }
}

extern "C" void kernel_launch(void* const* d_in, const int* in_sizes, int n_in,
                              void* d_out, int out_size, void* d_ws, size_t ws_size,
                              hipStream_t stream) {
    (void)in_sizes; (void)n_in; (void)out_size; (void)ws_size;
    const float* x    = (const float*)d_in[0];   // [B, F]
    const float* kern = (const float*)d_in[1];   // [F, A, F, U]
    float* out        = (float*)d_out;           // [A, B, F]
    unsigned char* ws = (unsigned char*)d_ws;    // ~4.1 MB used

    hipLaunchKernelGGL(ife_prep, dim3(F_ * A_), dim3(256), 0, stream, kern, ws);
    hipLaunchKernelGGL(ife_main, dim3(B_ / 64, A_), dim3(512), 0, stream, x, ws, out);
}